// Round 7
// baseline (163.683 us; speedup 1.0000x reference)
//
#include <hip/hip_runtime.h>
#include <cmath>

#define N_ 32
#define B_ 64
#define T_ 8192
#define REDSTRIDE 2176              // red: 1024 pp + 1024 pn + 4*32 stats
#define PARTSTRIDE 2048             // partial: Gram only (stats come from Pass A)

typedef float floatx4 __attribute__((ext_vector_type(4)));

// ---------------- Pass A: linear read -> fp8 relayout + exact fp32 row stats ----------
// grid 1024 x 256: wave = one contiguous row (32 KB), 4 consecutive rows per block ->
// perfectly linear global reads (the Gram-pair 2-MB-stride pathology moves to the
// writes, which are posted/fire-and-forget at full-256B-granule coalescing).
// W layout: [b][c][ci][tz][n][256B], c = 1024-t slice, ci = 256-t chunk; within each
// 256-B chunkrow, 8-B units are XOR-swizzled (unit^((n&7)<<1)) so Pass B's ds_reads
// are ~2-way-conflict-free while Pass B's DMA stays linear.
__global__ __launch_bounds__(256) void k_relayout(const float* __restrict__ pos,
                                                  const float* __restrict__ neg,
                                                  unsigned char* __restrict__ W,
                                                  float* __restrict__ red) {
    const int tid = threadIdx.x;
    const int wave = tid >> 6, lane = tid & 63;
    const int R = blockIdx.x * 4 + wave;        // 0..4095 global row
    const int tz = R >> 11;                     // 0 = pos, 1 = neg
    const int r = R & 2047;                     // n*64 + b
    const int n = r >> 6, b = r & 63;
    const float* src = (tz ? neg : pos) + (long)r * T_ + lane * 4;
    const int sw = (n & 7) << 1;
    const int k8 = lane >> 1, sub = lane & 1;   // lane's 4 B within the 256-B chunkrow
    unsigned char* dst0 = W + tz * 8192 + n * 256 + ((k8 ^ sw) << 3) + (sub << 2);

    float ssum = 0.f, ssq = 0.f;
    for (int g = 0; g < 8; ++g) {               // 8 groups x 4 chunkrows of 256 t
        float4 v[4];
#pragma unroll
        for (int u = 0; u < 4; ++u)
            v[u] = *(const float4*)(src + (g * 4 + u) * 256);
#pragma unroll
        for (int u = 0; u < 4; ++u) {
            const int it = g * 4 + u;           // chunkrow index 0..31
            const int c = it >> 2, ci = it & 3;
            float4 x = v[u];
            ssum += x.x + x.y + x.z + x.w;
            ssq = fmaf(x.x, x.x, ssq); ssq = fmaf(x.y, x.y, ssq);
            ssq = fmaf(x.z, x.z, ssq); ssq = fmaf(x.w, x.w, ssq);
            int pk = __builtin_amdgcn_cvt_pk_fp8_f32(x.x, x.y, 0, false);
            pk = __builtin_amdgcn_cvt_pk_fp8_f32(x.z, x.w, pk, true);
            *(int*)(dst0 + (size_t)(((b * 8 + c) * 4 + ci)) * 16384) = pk;
        }
    }

    // exact fp32 stats for this row (Pearson denominators stay full precision)
    ssum += __shfl_xor(ssum, 1); ssum += __shfl_xor(ssum, 2); ssum += __shfl_xor(ssum, 4);
    ssum += __shfl_xor(ssum, 8); ssum += __shfl_xor(ssum, 16); ssum += __shfl_xor(ssum, 32);
    ssq += __shfl_xor(ssq, 1); ssq += __shfl_xor(ssq, 2); ssq += __shfl_xor(ssq, 4);
    ssq += __shfl_xor(ssq, 8); ssq += __shfl_xor(ssq, 16); ssq += __shfl_xor(ssq, 32);
    if (lane == 0) {
        red[(long)b * REDSTRIDE + 2048 + tz * 64 + n] = ssum;        // sx / sy
        red[(long)b * REDSTRIDE + 2048 + tz * 64 + 32 + n] = ssq;    // sx2 / sy2
    }
}

// ---------------- Pass B: contiguous DMA -> LDS -> fp8 MFMA quadrant Grams ------------
// grid 512 = 64 b * 8 slices (1024 t); block 512 (8 waves). Each block reads a fully
// contiguous 64-KB span of W via pipelined global_load_lds (chunks of 16 KB).
// Wave = one 16x16 quadrant of pp or pn (verified structure from rounds 3-6).
__global__ __launch_bounds__(512, 4) void k_gram(const unsigned char* __restrict__ W,
                                                 float* __restrict__ partial) {
    __shared__ __align__(16) unsigned char smem[2][16384];

    const int bid = blockIdx.x;
    const int tid = threadIdx.x;
    const int wave = tid >> 6, lane = tid & 63;
    const int mat = wave >> 2, qi = (wave >> 1) & 1, qj = wave & 1;
    const int m16 = lane & 15, h2 = lane >> 4;
    const int arow = qi * 16 + m16, brow = qj * 16 + m16;
    const int aoff = arow * 256;                    // tensor 0 (pos)
    const int boff = mat * 8192 + brow * 256;
    const int swa = (arow & 7) << 1, swb = (brow & 7) << 1;
    const unsigned char* gsrc = W + (size_t)bid * 65536 + lane * 16;

    floatx4 acc = {};

#define ISSUE(ci, buf)                                                                \
    do {                                                                              \
        _Pragma("unroll") for (int g = 0; g < 2; ++g) {                               \
            __builtin_amdgcn_global_load_lds(                                         \
                (const __attribute__((address_space(1))) void*)(gsrc + (ci)*16384 +   \
                                                                wave * 2048 + g * 1024), \
                (__attribute__((address_space(3))) void*)(&smem[buf][wave * 2048 + g * 1024]), \
                16, 0, 0);                                                            \
        }                                                                             \
    } while (0)

    ISSUE(0, 0);
    ISSUE(1, 1);

    for (int ci = 0; ci < 4; ++ci) {
        const int buf = ci & 1;
        if (ci < 3) {
            asm volatile("s_waitcnt vmcnt(2)" ::: "memory");   // chunk ci landed; ci+1 in flight
        } else {
            asm volatile("s_waitcnt vmcnt(0)" ::: "memory");
        }
        asm volatile("s_barrier" ::: "memory");

        const unsigned char* base = smem[buf];
        // A layout (8 fp8/lane, analog of verified f16 16x16x32): A[m=lane&15][k=h2*8+j];
        // same layout both sides -> mfma(x,y) = X . Y^T.
#pragma unroll
        for (int kk = 0; kk < 8; ++kk) {
            const int u = kk * 4 + h2;                          // 8-B unit in chunkrow
            long long av = *(const long long*)(base + aoff + ((u ^ swa) << 3));
            long long bv = *(const long long*)(base + boff + ((u ^ swb) << 3));
            acc = __builtin_amdgcn_mfma_f32_16x16x32_fp8_fp8(av, bv, acc, 0, 0, 0);
        }

        asm volatile("s_barrier" ::: "memory");                 // reads of buf done
        if (ci + 2 < 4) ISSUE(ci + 2, buf);
    }
#undef ISSUE

    // C/D layout 16x16 (m89-verified, dtype-independent): col = lane&15, row = h2*4 + reg
    float* out = partial + (long)bid * PARTSTRIDE + mat * 1024;
#pragma unroll
    for (int reg = 0; reg < 4; ++reg) {
        int rr = qi * 16 + h2 * 4 + reg;
        int cc = qj * 16 + m16;
        out[rr * 32 + cc] = acc[reg];
    }
}

// ---------------- Stage 2: reduce 8 slice partials -> per-b Grams ----------------
__global__ void k_reduce(const float* __restrict__ partial, float* __restrict__ red) {
    const int b = blockIdx.y;
    const int o = blockIdx.x * 128 + threadIdx.x;   // 0..2047
    const float* in = partial + (long)b * 8 * PARTSTRIDE;
    float s = 0.f;
#pragma unroll
    for (int c = 0; c < 8; ++c) s += in[c * PARTSTRIDE + o];
    red[(long)b * REDSTRIDE + o] = s;
}

// ---------------- Stage 3: per-entry pearson over b, exp terms ----------------
__global__ void k_entries(const float* __restrict__ red, double* __restrict__ blocksums) {
    const int tid = threadIdx.x;
    const int w = tid >> 6, lane = tid & 63;
    const int entry = blockIdx.x * 4 + w;
    const int mat = entry >> 10;       // 0 = pp, 1 = pn
    const int idx = entry & 1023;
    const int n = idx >> 5, m = idx & 31;

    const float* rb = red + (long)lane * REDSTRIDE;
    float g = rb[mat * 1024 + idx];
    float sxn = rb[2048 + n];
    float sx2n = rb[2080 + n];
    float sym, sy2m;
    if (mat == 0) {
        sym = rb[2048 + m];
        sy2m = rb[2080 + m];
    } else {
        sym = rb[2112 + m];
        sy2m = rb[2144 + m];
    }

    double num = (double)T_ * (double)g - (double)sxn * (double)sym;
    double vx = (double)T_ * (double)sx2n - (double)sxn * (double)sxn;
    double vy = (double)T_ * (double)sy2m - (double)sym * (double)sym;
    double contrib = 1.0 - num / sqrt(vx * vy);

#pragma unroll
    for (int off = 32; off; off >>= 1) contrib += __shfl_down(contrib, off);

    __shared__ double s_pos[4], s_neg[4];
    if (lane == 0) {
        double d = contrib * (1.0 / B_);
        double term = exp(d / 0.08);
        double p = 0.0, q = 0.0;
        if (mat == 0) {
            if (n < m) p = term;     // strict upper triangle only
        } else {
            q = term;
        }
        s_pos[w] = p;
        s_neg[w] = q;
    }
    __syncthreads();
    if (tid == 0) {
        blocksums[blockIdx.x * 2 + 0] = s_pos[0] + s_pos[1] + s_pos[2] + s_pos[3];
        blocksums[blockIdx.x * 2 + 1] = s_neg[0] + s_neg[1] + s_neg[2] + s_neg[3];
    }
}

// ---------------- Stage 4: final scalar ----------------
__global__ void k_final(const double* __restrict__ blocksums, float* __restrict__ out) {
    __shared__ double sp[256], sn[256];
    const int tid = threadIdx.x;
    double p = 0.0, q = 0.0;
    for (int i = tid; i < 512; i += 256) {
        p += blocksums[2 * i + 0];
        q += blocksums[2 * i + 1];
    }
    sp[tid] = p;
    sn[tid] = q;
    __syncthreads();
    for (int s = 128; s; s >>= 1) {
        if (tid < s) {
            sp[tid] += sp[tid + s];
            sn[tid] += sn[tid + s];
        }
        __syncthreads();
    }
    if (tid == 0) out[0] = (float)log10(sp[0] / sn[0] + 1.0);
}

extern "C" void kernel_launch(void* const* d_in, const int* in_sizes, int n_in,
                              void* d_out, int out_size, void* d_ws, size_t ws_size,
                              hipStream_t stream) {
    const float* pos = (const float*)d_in[0];
    const float* neg = (const float*)d_in[1];
    float* out = (float*)d_out;

    char* ws = (char*)d_ws;
    unsigned char* W = (unsigned char*)ws;                          // 33,554,432 B
    float* partial = (float*)(ws + 33554432);                       //  4,194,304 B
    float* red = (float*)(ws + 33554432 + 4194304);                 //    557,056 B
    double* blocksums = (double*)(ws + 33554432 + 4194304 + 557056);//      8,192 B

    k_relayout<<<1024, 256, 0, stream>>>(pos, neg, W, red);
    k_gram<<<512, 512, 0, stream>>>(W, partial);
    k_reduce<<<dim3(16, 64), 128, 0, stream>>>(partial, red);
    k_entries<<<512, 256, 0, stream>>>(red, blocksums);
    k_final<<<1, 256, 0, stream>>>(blocksums, out);
}